// Round 13
// baseline (198.016 us; speedup 1.0000x reference)
//
#include <hip/hip_runtime.h>

typedef unsigned short u16;
typedef unsigned int u32;
typedef __attribute__((ext_vector_type(8))) short bf16x8;
typedef __attribute__((ext_vector_type(4))) float f32x4;
typedef __attribute__((ext_vector_type(16))) float f32x16;
typedef __attribute__((ext_vector_type(4))) u32 u32x4;

#define D_MODEL 1024
#define NHEAD 16
#define DHEAD 64
#define SEQ 2048
#define BATCH 4
#define MTOT (BATCH * SEQ) /* 8192 */
#define LOG2E 1.4426950408889634f

#define MFMA16(A, B, C) __builtin_amdgcn_mfma_f32_16x16x32_bf16((A), (B), (C), 0, 0, 0)
#define MFMA32(A, B, C) __builtin_amdgcn_mfma_f32_32x32x16_bf16((A), (B), (C), 0, 0, 0)

__device__ __forceinline__ u16 f2bf(float f) {
  u32 u = __builtin_bit_cast(u32, f);
  u = (u + 0x7FFFu + ((u >> 16) & 1u)) >> 16;
  return (u16)u;
}

// async global->LDS, 16B per lane. lds must be wave-uniform; g is per-lane.
__device__ __forceinline__ void async_copy16(void* lds, const void* g) {
  __builtin_amdgcn_global_load_lds(
      (const __attribute__((address_space(1))) u32*)g,
      (__attribute__((address_space(3))) u32*)lds, 16, 0, 0);
}

__device__ __forceinline__ u32 cvtpk_bf16(float lo, float hi) {
  u32 r;
  asm("v_cvt_pk_bf16_f32 %0, %1, %2" : "=v"(r) : "v"(lo), "v"(hi));
  return r;
}
// swaps a.hi32lanes <-> b.lo32lanes
__device__ __forceinline__ void permswap(u32& a, u32& b) {
  asm("v_permlane32_swap_b32 %0, %1" : "+v"(a), "+v"(b));
}

// raw workgroup barrier WITHOUT vmcnt drain (T4); memory-clobbered + sched-fenced
__device__ __forceinline__ void wg_barrier() {
  __builtin_amdgcn_sched_barrier(0);
  asm volatile("s_barrier" ::: "memory");
  __builtin_amdgcn_sched_barrier(0);
}
#define VMCNT(N) asm volatile("s_waitcnt vmcnt(" #N ")" ::: "memory")
#define LGKM0()  do { asm volatile("s_waitcnt lgkmcnt(0)" ::: "memory"); __builtin_amdgcn_sched_barrier(0); } while (0)

// ---------------- fp32 -> bf16 convert (all six tensors, one launch) ----------------
__global__ void cvt_all(const float* __restrict__ x, const float* __restrict__ ctx,
                        const float* __restrict__ Wq, const float* __restrict__ Wk,
                        const float* __restrict__ Wv, const float* __restrict__ Wo,
                        u16* __restrict__ xb, u16* __restrict__ cb,
                        u16* __restrict__ wqb, u16* __restrict__ wkb,
                        u16* __restrict__ wvb, u16* __restrict__ wob) {
  const int NX = 1 << 21;                 // x / ctx in float4 units (8M/4)
  const int NW = 1 << 18;                 // each weight in float4 units (1M/4)
  const int total = 2 * NX + 4 * NW;
  int i = blockIdx.x * blockDim.x + threadIdx.x;
  const int st = gridDim.x * blockDim.x;
  for (; i < total; i += st) {
    const float* s; u16* d; int j;
    if (i < NX)            { s = x;   d = xb;  j = i; }
    else if (i < 2 * NX)   { s = ctx; d = cb;  j = i - NX; }
    else {
      int k = i - 2 * NX;
      int wi = k >> 18;
      j = k & (NW - 1);
      s = (wi == 0) ? Wq : (wi == 1) ? Wk : (wi == 2) ? Wv : Wo;
      d = (wi == 0) ? wqb : (wi == 1) ? wkb : (wi == 2) ? wvb : wob;
    }
    float4 v = ((const float4*)s)[j];
    ushort4 o;
    o.x = f2bf(v.x); o.y = f2bf(v.y); o.z = f2bf(v.z); o.w = f2bf(v.w);
    ((ushort4*)d)[j] = o;
  }
}

// ================= 8-phase 256x128 NT-GEMM (T3+T4+T5) =================
// BM=256 BN=128 BK=64, 512 thr / 8 waves (4M x 2N), per-wave 64x64 out (4x4 MFMA16).
// LDS: 3 buffers x (A 32KB + B 16KB) = 144KB. Prefetch distance 2 K-tiles:
// stage(t+2) -> buf[(t+2)%3] never aliases read buf[t%3]. VMCNT(6) once per K-tile
// (6 loads/thread/tile), placed before the last phase's trailing barrier; never 0
// in steady state. Each phase: 8 ds_read || 1-2 gload_lds || barrier || lgkm0 ||
// setprio(1) 8xMFMA setprio(0) || barrier.
// MODE 0: fused QKV (Q: qknorm*log2e -> Qb; K: qknorm -> Kb; V: bias+transpose -> Vtb)
// MODE 1: f32 out-projection (A=attn-out, Bw=Wo, bias=bo -> fout)
#define BM8 256
#define BN8 128
#define BK8 64
#define GK 1024
#define NIT (GK / BK8)            /* 16 */
#define ABYTES (BM8 * BK8 * 2)    /* 32768 */
#define BUFB (ABYTES + BN8 * BK8 * 2) /* 49152 */

template <int MODE>
__global__ __launch_bounds__(512, 2) void gemm8p(
    const u16* __restrict__ xb, const u16* __restrict__ cb,
    const u16* __restrict__ wqb, const u16* __restrict__ wkvb,
    const float* __restrict__ bq, const float* __restrict__ bk,
    const float* __restrict__ bvv,
    u16* __restrict__ Qb, u16* __restrict__ Kb, u16* __restrict__ Vtb,
    float* __restrict__ fout) {
  __shared__ alignas(16) char ldsbuf[3 * BUFB]; // 144KB -> 1 block/CU
  const int tid = threadIdx.x;
  const int l = tid & 63;
  const int wid = tid >> 6;      // 0..7
  const int bid = blockIdx.x;
  const u16 *A, *Bw;
  int m0, n0;
  bool isQ = false;
  if (MODE == 0) {
    const int swz = (bid & 7) * 96 + (bid >> 3); // 768 = 8*96 bijective
    isQ = swz < 256;
    if (isQ) { A = xb; Bw = wqb; m0 = (swz >> 3) * BM8; n0 = (swz & 7) * BN8; }
    else { const int s = swz - 256; A = cb; Bw = wkvb; m0 = (s >> 4) * BM8; n0 = (s & 15) * BN8; }
  } else {
    const int swz = (bid & 7) * 32 + (bid >> 3); // 256 = 8*32
    A = xb; Bw = wqb;
    m0 = (swz >> 3) * BM8; n0 = (swz & 7) * BN8;
  }
  const int wr = wid >> 1, wc = wid & 1;
  const int r = l & 15, kg = l >> 4;
  const int arow8 = l >> 3;
  const int agran = (l & 7) ^ arow8;   // inverse-swizzled source granule (g^=(row&7))

  // 6 strength-reduced stage pointers; +64 elems (128B) per K-tile
  const u16* pA0 = A + (size_t)(m0 + (wid + 0) * 8 + arow8) * GK + agran * 8;
  const u16* pA1 = A + (size_t)(m0 + (wid + 8) * 8 + arow8) * GK + agran * 8;
  const u16* pA2 = A + (size_t)(m0 + (wid + 16) * 8 + arow8) * GK + agran * 8;
  const u16* pA3 = A + (size_t)(m0 + (wid + 24) * 8 + arow8) * GK + agran * 8;
  const u16* pB0 = Bw + (size_t)(n0 + (wid + 0) * 8 + arow8) * GK + agran * 8;
  const u16* pB1 = Bw + (size_t)(n0 + (wid + 8) * 8 + arow8) * GK + agran * 8;

  f32x4 acc[4][4] = {};

  // part p of staging one K-tile into buffer base (A: chunks wid, wid+8, wid+16, wid+24; B: wid, wid+8)
  auto stage_part = [&](char* base, int p) {
    if (p == 0) {
      async_copy16(base + (wid + 0) * 1024, pA0);
      async_copy16(base + (wid + 8) * 1024, pA1);
    } else if (p == 1) {
      async_copy16(base + (wid + 16) * 1024, pA2);
      async_copy16(base + (wid + 24) * 1024, pA3);
    } else if (p == 2) {
      async_copy16(base + ABYTES + (wid + 0) * 1024, pB0);
    } else {
      async_copy16(base + ABYTES + (wid + 8) * 1024, pB1);
      pA0 += 64; pA1 += 64; pA2 += 64; pA3 += 64; pB0 += 64; pB1 += 64;
    }
  };

  // one phase: quadrant (ih,jh), optional stage part, vm: 0 none / 1 vmcnt6 / 2 vmcnt0
  auto phase = [&](const char* rb, int ih, int jh, char* sb, int sp, bool ds, int vm) {
    const char* Ab = rb;
    const char* Bb = rb + ABYTES;
    bf16x8 af[2][2], bf[2][2];
#pragma unroll
    for (int ii = 0; ii < 2; ++ii) {
      const int rowA = wr * 64 + (ih * 2 + ii) * 16 + r;
#pragma unroll
      for (int hf = 0; hf < 2; ++hf) {
        const int g = ((hf << 2) + kg) ^ (r & 7);
        af[ii][hf] = *(const bf16x8*)(Ab + rowA * 128 + g * 16);
      }
    }
#pragma unroll
    for (int jj = 0; jj < 2; ++jj) {
      const int rowB = wc * 64 + (jh * 2 + jj) * 16 + r;
#pragma unroll
      for (int hf = 0; hf < 2; ++hf) {
        const int g = ((hf << 2) + kg) ^ (r & 7);
        bf[jj][hf] = *(const bf16x8*)(Bb + rowB * 128 + g * 16);
      }
    }
    if (ds) stage_part(sb, sp);
    wg_barrier();
    LGKM0();
    __builtin_amdgcn_s_setprio(1);
#pragma unroll
    for (int hf = 0; hf < 2; ++hf)
#pragma unroll
      for (int ii = 0; ii < 2; ++ii)
#pragma unroll
        for (int jj = 0; jj < 2; ++jj)
          acc[ih * 2 + ii][jh * 2 + jj] =
              MFMA16(af[ii][hf], bf[jj][hf], acc[ih * 2 + ii][jh * 2 + jj]);
    __builtin_amdgcn_s_setprio(0);
    if (vm == 1) { VMCNT(6); }
    else if (vm == 2) { VMCNT(0); }
    wg_barrier();
  };

  char* b0 = ldsbuf;
  char* b1 = ldsbuf + BUFB;
  char* b2 = ldsbuf + 2 * BUFB;

  // prologue: stage tiles 0,1 fully; wait tile0 (6 of 12), barrier
#pragma unroll
  for (int p = 0; p < 4; ++p) stage_part(b0, p);
#pragma unroll
  for (int p = 0; p < 4; ++p) stage_part(b1, p);
  VMCNT(6);
  wg_barrier();

  int rm = 0; // t % 3
  for (int t = 0; t < NIT; ++t) {
    char* rb = (rm == 0) ? b0 : (rm == 1) ? b1 : b2;
    char* sb = (rm == 0) ? b2 : (rm == 1) ? b0 : b1; // (t+2)%3
    const bool ds = (t + 2 < NIT);
    const int vml = (t < NIT - 2) ? 1 : (t == NIT - 2) ? 2 : 0;
    phase(rb, 0, 0, sb, 0, ds, 0);
    phase(rb, 0, 1, sb, 1, ds, 0);
    phase(rb, 1, 0, sb, 2, ds, 0);
    phase(rb, 1, 1, sb, 3, ds, vml);
    rm = (rm == 2) ? 0 : rm + 1;
  }

  // ---------------- epilogues ----------------
  if (MODE == 1) {
    const int N = 1024;
#pragma unroll
    for (int i = 0; i < 4; ++i) {
#pragma unroll
      for (int j = 0; j < 4; ++j) {
        const int col = n0 + wc * 64 + j * 16 + r;
        const float bb = bq[col];
        const int row0 = m0 + wr * 64 + i * 16 + kg * 4;
#pragma unroll
        for (int jj = 0; jj < 4; ++jj)
          fout[(size_t)(row0 + jj) * N + col] = acc[i][j][jj] + bb;
      }
    }
    return;
  }
  const int colbase = n0 + wc * 64;
  const bool isV = (!isQ) && (colbase >= 1024);
  if (!isV) {
    u16* C = isQ ? Qb : Kb;
    const float* bias = isQ ? bq : bk;
    const float sMul = isQ ? LOG2E : 1.0f;
    float bvj[4];
#pragma unroll
    for (int j = 0; j < 4; ++j) bvj[j] = bias[colbase + j * 16 + r];
#pragma unroll
    for (int i = 0; i < 4; ++i) {
      const int row0 = m0 + wr * 64 + i * 16 + kg * 4;
#pragma unroll
      for (int jj = 0; jj < 4; ++jj) {
        float tv[4];
        float s2 = 0.f;
#pragma unroll
        for (int j = 0; j < 4; ++j) {
          tv[j] = acc[i][j][jj] + bvj[j];
          s2 += tv[j] * tv[j];
        }
        s2 += __shfl_xor(s2, 1);
        s2 += __shfl_xor(s2, 2);
        s2 += __shfl_xor(s2, 4);
        s2 += __shfl_xor(s2, 8);
        const float inv = sMul / (sqrtf(s2) + 1e-6f);
#pragma unroll
        for (int j = 0; j < 4; ++j)
          C[(size_t)(row0 + jj) * D_MODEL + colbase + j * 16 + r] = f2bf(tv[j] * inv);
      }
    }
  } else {
#pragma unroll
    for (int i = 0; i < 4; ++i) {
#pragma unroll
      for (int j = 0; j < 4; ++j) {
        const int col = colbase + j * 16 + r;      // 1024..2047
        const float bb = bvv[col - 1024];
        const int row0 = m0 + wr * 64 + i * 16 + kg * 4;
        const int hh = (col - 1024) >> 6, dh = col & 63;
        const int bbk = row0 >> 11, tok = row0 & 2047;
        ushort4 o;
        o.x = f2bf(acc[i][j][0] + bb);
        o.y = f2bf(acc[i][j][1] + bb);
        o.z = f2bf(acc[i][j][2] + bb);
        o.w = f2bf(acc[i][j][3] + bb);
        *(ushort4*)(Vtb + ((size_t)((bbk * 16 + hh) * 64 + dh) * SEQ + tok)) = o;
      }
    }
  }
}

// ---------------- flash attention v12 (round-12 best: 81.3 us) ----------------
#define KVB 64
#define NT (SEQ / KVB)

__global__ __launch_bounds__(256, 4) void attn_kernel(const u16* __restrict__ Q,
                                                      const u16* __restrict__ K,
                                                      const u16* __restrict__ Vt,
                                                      u16* __restrict__ O) {
  __shared__ alignas(16) u16 Ks[2][KVB * 64]; // 2 x 8KB
  __shared__ alignas(16) u16 Vs[2][64 * KVB]; // 2 x 8KB
  const int tid = threadIdx.x;
  const int l = tid & 63;
  const int wid = tid >> 6;
  const int qg = l & 31;
  const int half = l >> 5;
  const int bid = blockIdx.x;
  const int swz = (bid & 7) * 128 + (bid >> 3);
  const int qt = swz & 15;
  const int bh = swz >> 4;
  const int b = bh >> 4, h = bh & 15;

  const int srow = l >> 3, slot = l & 7;
  const int r0 = (wid << 3) + srow;
  const int r1 = ((wid + 4) << 3) + srow;
  const int sw0 = (r0 ^ (r0 >> 3)) & 7;
  const int sw1 = (r1 ^ (r1 >> 3)) & 7;
  const u16* pK0 = K + ((size_t)(b * SEQ) + r0) * D_MODEL + h * 64 + (slot ^ sw0) * 8;
  const u16* pK1 = K + ((size_t)(b * SEQ) + r1) * D_MODEL + h * 64 + (slot ^ sw1) * 8;
  const u16* pV0 = Vt + ((size_t)(bh * 64) + r0) * SEQ + (slot ^ sw0) * 8;
  const u16* pV1 = Vt + ((size_t)(bh * 64) + r1) * SEQ + (slot ^ sw1) * 8;
  const int ldsc0 = wid * 1024, ldsc1 = (wid + 4) * 1024;

  bf16x8 qf[4];
  {
    const u16* q0 = Q + ((size_t)(b * SEQ + qt * 128 + wid * 32 + qg)) * D_MODEL + h * 64 + half * 8;
#pragma unroll
    for (int dc = 0; dc < 4; ++dc) qf[dc] = *(const bf16x8*)(q0 + dc * 16);
  }

  int koff[2][4], voff[2][2][2];
#pragma unroll
  for (int t32 = 0; t32 < 2; ++t32) {
    const int rowK = t32 * 32 + qg;
    const int swk = (rowK ^ (rowK >> 3)) & 7;
#pragma unroll
    for (int dc = 0; dc < 4; ++dc)
      koff[t32][dc] = rowK * 128 + (((dc * 2 + half) ^ swk) << 4);
#pragma unroll
    for (int cc = 0; cc < 2; ++cc) {
      const int qw = ((t32 * 2 + cc) << 1) + half;
#pragma unroll
      for (int dt = 0; dt < 2; ++dt) {
        const int rowV = dt * 32 + qg;
        voff[t32][cc][dt] = rowV * 128 + ((qw ^ ((rowV ^ (rowV >> 3)) & 7)) << 4);
      }
    }
  }

  f32x16 oacc[2] = {};
  float lrun = 0.f;

  auto stage = [&](int bufi) {
    char* KsX = (char*)Ks[bufi];
    char* VsX = (char*)Vs[bufi];
    async_copy16(KsX + ldsc0, pK0);
    async_copy16(KsX + ldsc1, pK1);
    async_copy16(VsX + ldsc0, pV0);
    async_copy16(VsX + ldsc1, pV1);
    pK0 += (size_t)KVB * D_MODEL;
    pK1 += (size_t)KVB * D_MODEL;
    pV0 += KVB;
    pV1 += KVB;
  };

  auto process = [&](const char* KsC, const char* VsC) {
    f32x16 st[2] = {};
    __builtin_amdgcn_s_setprio(1);
#pragma unroll
    for (int t32 = 0; t32 < 2; ++t32)
#pragma unroll
      for (int dc = 0; dc < 4; ++dc) {
        bf16x8 kf = *(const bf16x8*)(KsC + koff[t32][dc]);
        st[t32] = MFMA32(kf, qf[dc], st[t32]);
      }
    __builtin_amdgcn_s_setprio(0);

    float rs0 = 0.f, rs1 = 0.f, rs2 = 0.f, rs3 = 0.f;
#pragma unroll
    for (int t32 = 0; t32 < 2; ++t32)
#pragma unroll
      for (int rr = 0; rr < 16; rr += 4) {
        float p0 = __builtin_amdgcn_exp2f(st[t32][rr + 0]);
        float p1 = __builtin_amdgcn_exp2f(st[t32][rr + 1]);
        float p2 = __builtin_amdgcn_exp2f(st[t32][rr + 2]);
        float p3 = __builtin_amdgcn_exp2f(st[t32][rr + 3]);
        st[t32][rr + 0] = p0; st[t32][rr + 1] = p1;
        st[t32][rr + 2] = p2; st[t32][rr + 3] = p3;
        rs0 += p0; rs1 += p1; rs2 += p2; rs3 += p3;
      }
    lrun += (rs0 + rs1) + (rs2 + rs3);

#pragma unroll
    for (int t32 = 0; t32 < 2; ++t32) {
#pragma unroll
      for (int cc = 0; cc < 2; ++cc) {
        const int base = cc * 8;
        u32 wA = cvtpk_bf16(st[t32][base + 0], st[t32][base + 1]);
        u32 wB = cvtpk_bf16(st[t32][base + 2], st[t32][base + 3]);
        u32 wC = cvtpk_bf16(st[t32][base + 4], st[t32][base + 5]);
        u32 wD = cvtpk_bf16(st[t32][base + 6], st[t32][base + 7]);
        permswap(wA, wC);
        permswap(wB, wD);
        u32x4 pw = {wA, wB, wC, wD};
        bf16x8 pf = __builtin_bit_cast(bf16x8, pw);
        __builtin_amdgcn_s_setprio(1);
#pragma unroll
        for (int dt = 0; dt < 2; ++dt) {
          bf16x8 vf = *(const bf16x8*)(VsC + voff[t32][cc][dt]);
          oacc[dt] = MFMA32(vf, pf, oacc[dt]);
        }
        __builtin_amdgcn_s_setprio(0);
      }
    }
  };

  stage(0);
  stage(1);
  VMCNT(0);
  wg_barrier();

  for (int tp = 0; tp < NT / 2 - 1; ++tp) {
    VMCNT(4);
    wg_barrier();
    process((const char*)Ks[0], (const char*)Vs[0]);
    wg_barrier();
    stage(0);
    VMCNT(4);
    wg_barrier();
    process((const char*)Ks[1], (const char*)Vs[1]);
    wg_barrier();
    stage(1);
  }
  VMCNT(4);
  wg_barrier();
  process((const char*)Ks[0], (const char*)Vs[0]);
  wg_barrier();
  VMCNT(0);
  wg_barrier();
  process((const char*)Ks[1], (const char*)Vs[1]);

  lrun += __shfl_xor(lrun, 32);
  const float inv = 1.0f / lrun;
  u32* orow = (u32*)(O + ((size_t)(b * SEQ + qt * 128 + wid * 32 + qg)) * D_MODEL + h * 64);
#pragma unroll
  for (int dt = 0; dt < 2; ++dt)
#pragma unroll
    for (int w = 0; w < 8; ++w) {
      const int dh = dt * 32 + (w & 1) * 2 + 8 * (w >> 1) + 4 * half;
      u32 pk = cvtpk_bf16(oacc[dt][2 * w] * inv, oacc[dt][2 * w + 1] * inv);
      orow[dh >> 1] = pk;
    }
}

// ---------------- launch ----------------
extern "C" void kernel_launch(void* const* d_in, const int* in_sizes, int n_in,
                              void* d_out, int out_size, void* d_ws, size_t ws_size,
                              hipStream_t stream) {
  const float* x   = (const float*)d_in[0];
  const float* ctx = (const float*)d_in[1];
  const float* Wq  = (const float*)d_in[2];
  const float* bq  = (const float*)d_in[3];
  const float* Wk  = (const float*)d_in[4];
  const float* bk  = (const float*)d_in[5];
  const float* Wv  = (const float*)d_in[6];
  const float* bv  = (const float*)d_in[7];
  const float* Wo  = (const float*)d_in[8];
  const float* bo  = (const float*)d_in[9];
  float* out = (float*)d_out;

  const size_t NTOK = (size_t)MTOT * D_MODEL; // 8M elems
  const size_t WSZ = (size_t)D_MODEL * D_MODEL;
  u16* xb  = (u16*)d_ws;       // x bf16; later reused as attention output
  u16* cb  = xb + NTOK;
  u16* wqb = cb + NTOK;
  u16* wkb = wqb + WSZ;        // wk,wv adjacent -> fused [K|V] GEMM B-panel
  u16* wvb = wkb + WSZ;
  u16* wob = wvb + WSZ;
  u16* Qb  = wob + WSZ;
  u16* Kb  = Qb + NTOK;
  u16* Vtb = Kb + NTOK;        // [b*16+h][dh][tok]
  (void)in_sizes; (void)n_in; (void)out_size; (void)ws_size;

  cvt_all<<<2048, 256, 0, stream>>>(x, ctx, Wq, Wk, Wv, Wo, xb, cb, wqb, wkb, wvb, wob);

  gemm8p<0><<<768, 512, 0, stream>>>(xb, cb, wqb, wkb, bq, bk, bv, Qb, Kb, Vtb, nullptr);

  attn_kernel<<<1024, 256, 0, stream>>>(Qb, Kb, Vtb, xb);

  gemm8p<1><<<256, 512, 0, stream>>>(xb, nullptr, wob, nullptr, bo, nullptr, nullptr,
                                     nullptr, nullptr, nullptr, out);
}

// Round 14
// 177.042 us; speedup vs baseline: 1.1185x; 1.1185x over previous
//
#include <hip/hip_runtime.h>

typedef unsigned short u16;
typedef unsigned int u32;
typedef __attribute__((ext_vector_type(8))) short bf16x8;
typedef __attribute__((ext_vector_type(4))) float f32x4;
typedef __attribute__((ext_vector_type(16))) float f32x16;
typedef __attribute__((ext_vector_type(4))) u32 u32x4;

#define D_MODEL 1024
#define NHEAD 16
#define DHEAD 64
#define SEQ 2048
#define BATCH 4
#define MTOT (BATCH * SEQ) /* 8192 */
#define LOG2E 1.4426950408889634f

#define MFMA16(A, B, C) __builtin_amdgcn_mfma_f32_16x16x32_bf16((A), (B), (C), 0, 0, 0)
#define MFMA32(A, B, C) __builtin_amdgcn_mfma_f32_32x32x16_bf16((A), (B), (C), 0, 0, 0)

__device__ __forceinline__ u16 f2bf(float f) {
  u32 u = __builtin_bit_cast(u32, f);
  u = (u + 0x7FFFu + ((u >> 16) & 1u)) >> 16;
  return (u16)u;
}

// async global->LDS, 16B per lane. lds must be wave-uniform; g is per-lane.
__device__ __forceinline__ void async_copy16(void* lds, const void* g) {
  __builtin_amdgcn_global_load_lds(
      (const __attribute__((address_space(1))) u32*)g,
      (__attribute__((address_space(3))) u32*)lds, 16, 0, 0);
}

__device__ __forceinline__ u32 cvtpk_bf16(float lo, float hi) {
  u32 r;
  asm("v_cvt_pk_bf16_f32 %0, %1, %2" : "=v"(r) : "v"(lo), "v"(hi));
  return r;
}
// swaps a.hi32lanes <-> b.lo32lanes
__device__ __forceinline__ void permswap(u32& a, u32& b) {
  asm("v_permlane32_swap_b32 %0, %1" : "+v"(a), "+v"(b));
}

// raw workgroup barrier WITHOUT vmcnt drain (T4); memory-clobbered + sched-fenced
__device__ __forceinline__ void wg_barrier() {
  __builtin_amdgcn_sched_barrier(0);
  asm volatile("s_barrier" ::: "memory");
  __builtin_amdgcn_sched_barrier(0);
}
#define VMCNT(N) asm volatile("s_waitcnt vmcnt(" #N ")" ::: "memory")

// ---------------- fp32 -> bf16 convert (all six tensors, one launch) ----------------
__global__ void cvt_all(const float* __restrict__ x, const float* __restrict__ ctx,
                        const float* __restrict__ Wq, const float* __restrict__ Wk,
                        const float* __restrict__ Wv, const float* __restrict__ Wo,
                        u16* __restrict__ xb, u16* __restrict__ cb,
                        u16* __restrict__ wqb, u16* __restrict__ wkb,
                        u16* __restrict__ wvb, u16* __restrict__ wob) {
  const int NX = 1 << 21;                 // x / ctx in float4 units (8M/4)
  const int NW = 1 << 18;                 // each weight in float4 units (1M/4)
  const int total = 2 * NX + 4 * NW;
  int i = blockIdx.x * blockDim.x + threadIdx.x;
  const int st = gridDim.x * blockDim.x;
  for (; i < total; i += st) {
    const float* s; u16* d; int j;
    if (i < NX)            { s = x;   d = xb;  j = i; }
    else if (i < 2 * NX)   { s = ctx; d = cb;  j = i - NX; }
    else {
      int k = i - 2 * NX;
      int wi = k >> 18;
      j = k & (NW - 1);
      s = (wi == 0) ? Wq : (wi == 1) ? Wk : (wi == 2) ? Wv : Wo;
      d = (wi == 0) ? wqb : (wi == 1) ? wkb : (wi == 2) ? wvb : wob;
    }
    float4 v = ((const float4*)s)[j];
    ushort4 o;
    o.x = f2bf(v.x); o.y = f2bf(v.y); o.z = f2bf(v.z); o.w = f2bf(v.w);
    ((ushort4*)d)[j] = o;
  }
}

// ================= fused QKV NT-GEMM =================
// grid 1536: swz<512 -> Q = x·Wq^T (+bq, qknorm, *log2e) -> Qb
//            swz>=512 -> [K|V] = ctx·[Wk;Wv]^T; cols<1024: K (+bk, qknorm) -> Kb
//                                               cols>=1024: V (+bv, transposed) -> Vtb
__global__ __launch_bounds__(256, 4) void gemm_qkv(
    const u16* __restrict__ xb, const u16* __restrict__ cb,
    const u16* __restrict__ wqb, const u16* __restrict__ wkvb,
    const float* __restrict__ bq, const float* __restrict__ bk,
    const float* __restrict__ bv,
    u16* __restrict__ Qb, u16* __restrict__ Kb, u16* __restrict__ Vtb) {
  __shared__ u16 As[128 * 64]; // 16KB, rows 128B, granule-swizzled g^=(row&7)
  __shared__ u16 Bs[128 * 64]; // 16KB
  const int K = 1024;
  const int tid = threadIdx.x;
  const int l = tid & 63;
  const int wid = tid >> 6;
  const int bid = blockIdx.x;
  const int swz = (bid & 7) * 192 + (bid >> 3); // 1536 = 8 * 192, bijective
  const bool isQ = swz < 512;
  const u16* A;
  const u16* Bw;
  int m0, n0;
  if (isQ) {
    A = xb; Bw = wqb;
    m0 = (swz >> 3) * 128;       // 64 m-tiles
    n0 = (swz & 7) * 128;        // 8 n-tiles
  } else {
    const int s = swz - 512;
    A = cb; Bw = wkvb;
    m0 = (s >> 4) * 128;         // 64 m-tiles
    n0 = (s & 15) * 128;         // 16 n-tiles (N=2048)
  }
  const int wr = wid >> 1, wc = wid & 1;
  const int r = l & 15, kg = l >> 4;
  f32x4 acc[4][4] = {};
  char* AsB = (char*)As;
  char* BsB = (char*)Bs;
  const int arow = l >> 3;
  const int agran = (l & 7) ^ arow;

  for (int kt = 0; kt < K; kt += 64) {
#pragma unroll
    for (int cc = 0; cc < 4; ++cc) {
      int c = wid + (cc << 2);
      int rowi = (c << 3) + arow;
      const char* ga = (const char*)A + ((size_t)(m0 + rowi) * K + kt) * 2 + agran * 16;
      async_copy16(AsB + c * 1024, ga);
      const char* gb = (const char*)Bw + ((size_t)(n0 + rowi) * K + kt) * 2 + agran * 16;
      async_copy16(BsB + c * 1024, gb);
    }
    __syncthreads();
#pragma unroll
    for (int half = 0; half < 2; ++half) {
      const int g = ((half << 2) + kg) ^ (r & 7);
      bf16x8 af[4], bf[4];
#pragma unroll
      for (int i = 0; i < 4; ++i) {
        af[i] = *(const bf16x8*)(AsB + (wr * 64 + i * 16 + r) * 128 + g * 16);
        bf[i] = *(const bf16x8*)(BsB + (wc * 64 + i * 16 + r) * 128 + g * 16);
      }
#pragma unroll
      for (int i = 0; i < 4; ++i)
#pragma unroll
        for (int j = 0; j < 4; ++j)
          acc[i][j] = MFMA16(af[i], bf[j], acc[i][j]);
    }
    __syncthreads();
  }

  const int colbase = n0 + wc * 64;
  const bool isV = (!isQ) && (colbase >= 1024);
  if (!isV) {
    // qknorm epilogue (Q or K): wave owns one 64-col head group per row
    u16* C = isQ ? Qb : Kb;
    const float* bias = isQ ? bq : bk;
    const float sMul = isQ ? LOG2E : 1.0f;
    float bvj[4];
#pragma unroll
    for (int j = 0; j < 4; ++j) bvj[j] = bias[colbase + j * 16 + r];
#pragma unroll
    for (int i = 0; i < 4; ++i) {
      const int row0 = m0 + wr * 64 + i * 16 + kg * 4;
#pragma unroll
      for (int jj = 0; jj < 4; ++jj) {
        float t[4];
        float s2 = 0.f;
#pragma unroll
        for (int j = 0; j < 4; ++j) {
          t[j] = acc[i][j][jj] + bvj[j];
          s2 += t[j] * t[j];
        }
        s2 += __shfl_xor(s2, 1);
        s2 += __shfl_xor(s2, 2);
        s2 += __shfl_xor(s2, 4);
        s2 += __shfl_xor(s2, 8);
        const float inv = sMul / (sqrtf(s2) + 1e-6f);
#pragma unroll
        for (int j = 0; j < 4; ++j)
          C[(size_t)(row0 + jj) * D_MODEL + colbase + j * 16 + r] = f2bf(t[j] * inv);
      }
    }
  } else {
    // V transposed store: Vt[(b*16+h)*64 + dh][tok], 4 consecutive tok per lane
#pragma unroll
    for (int i = 0; i < 4; ++i) {
#pragma unroll
      for (int j = 0; j < 4; ++j) {
        const int col = colbase + j * 16 + r;      // 1024..2047
        const float bvv = bv[col - 1024];
        const int row0 = m0 + wr * 64 + i * 16 + kg * 4;
        const int hh = (col - 1024) >> 6, dh = col & 63;
        const int bb = row0 >> 11, tok = row0 & 2047;
        ushort4 o;
        o.x = f2bf(acc[i][j][0] + bvv);
        o.y = f2bf(acc[i][j][1] + bvv);
        o.z = f2bf(acc[i][j][2] + bvv);
        o.w = f2bf(acc[i][j][3] + bvv);
        *(ushort4*)(Vtb + ((size_t)((bb * 16 + hh) * 64 + dh) * SEQ + tok)) = o;
      }
    }
  }
}

// ================= output-projection NT-GEMM (f32 out) =================
__global__ __launch_bounds__(256, 4) void gemm_out(const u16* __restrict__ A,
                                                   const u16* __restrict__ Bw,
                                                   const float* __restrict__ bias,
                                                   float* __restrict__ Cout) {
  __shared__ u16 As[128 * 64];
  __shared__ u16 Bs[128 * 64];
  const int K = 1024, N = 1024;
  const int tid = threadIdx.x;
  const int l = tid & 63;
  const int wid = tid >> 6;
  const int bid = blockIdx.x;
  const int swz = (bid & 7) * 64 + (bid >> 3); // 512 = 8 * 64
  const int m0 = (swz >> 3) * 128;
  const int n0 = (swz & 7) * 128;
  const int wr = wid >> 1, wc = wid & 1;
  const int r = l & 15, kg = l >> 4;
  f32x4 acc[4][4] = {};
  char* AsB = (char*)As;
  char* BsB = (char*)Bs;
  const int arow = l >> 3;
  const int agran = (l & 7) ^ arow;

  for (int kt = 0; kt < K; kt += 64) {
#pragma unroll
    for (int cc = 0; cc < 4; ++cc) {
      int c = wid + (cc << 2);
      int rowi = (c << 3) + arow;
      const char* ga = (const char*)A + ((size_t)(m0 + rowi) * K + kt) * 2 + agran * 16;
      async_copy16(AsB + c * 1024, ga);
      const char* gb = (const char*)Bw + ((size_t)(n0 + rowi) * K + kt) * 2 + agran * 16;
      async_copy16(BsB + c * 1024, gb);
    }
    __syncthreads();
#pragma unroll
    for (int half = 0; half < 2; ++half) {
      const int g = ((half << 2) + kg) ^ (r & 7);
      bf16x8 af[4], bf[4];
#pragma unroll
      for (int i = 0; i < 4; ++i) {
        af[i] = *(const bf16x8*)(AsB + (wr * 64 + i * 16 + r) * 128 + g * 16);
        bf[i] = *(const bf16x8*)(BsB + (wc * 64 + i * 16 + r) * 128 + g * 16);
      }
#pragma unroll
      for (int i = 0; i < 4; ++i)
#pragma unroll
        for (int j = 0; j < 4; ++j)
          acc[i][j] = MFMA16(af[i], bf[j], acc[i][j]);
    }
    __syncthreads();
  }
#pragma unroll
  for (int i = 0; i < 4; ++i) {
#pragma unroll
    for (int j = 0; j < 4; ++j) {
      const int col = n0 + wc * 64 + j * 16 + r;
      const float bvv = bias[col];
      const int row0 = m0 + wr * 64 + i * 16 + kg * 4;
#pragma unroll
      for (int jj = 0; jj < 4; ++jj)
        Cout[(size_t)(row0 + jj) * N + col] = acc[i][j][jj] + bvv;
    }
  }
}

// ---------------- flash attention v12 (round-12 best: 81.3 us) ----------------
// Round-9 pipeline (KVB=64, 4 blocks/CU, counted vmcnt, raw barriers) + precomputed
// swizzled LDS offsets + pair-unrolled loop (compile-time buffer bases).
#define KVB 64
#define NT (SEQ / KVB)

__global__ __launch_bounds__(256, 4) void attn_kernel(const u16* __restrict__ Q,
                                                      const u16* __restrict__ K,
                                                      const u16* __restrict__ Vt,
                                                      u16* __restrict__ O) {
  __shared__ alignas(16) u16 Ks[2][KVB * 64]; // 2 x 8KB
  __shared__ alignas(16) u16 Vs[2][64 * KVB]; // 2 x 8KB
  const int tid = threadIdx.x;
  const int l = tid & 63;
  const int wid = tid >> 6;
  const int qg = l & 31;     // q row within wave
  const int half = l >> 5;
  // XCD-chunked grid: each XCD gets 128 consecutive swz = 8 bh values (K/V L2-resident)
  const int bid = blockIdx.x;
  const int swz = (bid & 7) * 128 + (bid >> 3);
  const int qt = swz & 15;   // 0..15
  const int bh = swz >> 4;   // 0..63
  const int b = bh >> 4, h = bh & 15;

  // ---- stage geometry: wave handles K chunks {wid, wid+4} and V chunks {wid, wid+4}
  const int srow = l >> 3, slot = l & 7;
  const int r0 = (wid << 3) + srow;
  const int r1 = ((wid + 4) << 3) + srow;
  const int sw0 = (r0 ^ (r0 >> 3)) & 7;
  const int sw1 = (r1 ^ (r1 >> 3)) & 7;
  const u16* pK0 = K + ((size_t)(b * SEQ) + r0) * D_MODEL + h * 64 + (slot ^ sw0) * 8;
  const u16* pK1 = K + ((size_t)(b * SEQ) + r1) * D_MODEL + h * 64 + (slot ^ sw1) * 8;
  const u16* pV0 = Vt + ((size_t)(bh * 64) + r0) * SEQ + (slot ^ sw0) * 8;
  const u16* pV1 = Vt + ((size_t)(bh * 64) + r1) * SEQ + (slot ^ sw1) * 8;
  const int ldsc0 = wid * 1024, ldsc1 = (wid + 4) * 1024;

  // Q fragments (pre-scaled by log2e at GEMM): col=q=l&31, k = dc*16 + half*8 + e
  bf16x8 qf[4];
  {
    const u16* q0 = Q + ((size_t)(b * SEQ + qt * 128 + wid * 32 + qg)) * D_MODEL + h * 64 + half * 8;
#pragma unroll
    for (int dc = 0; dc < 4; ++dc) qf[dc] = *(const bf16x8*)(q0 + dc * 16);
  }

  // precomputed LDS byte offsets (lane-invariant across tiles): 16 ints
  int koff[2][4], voff[2][2][2];
#pragma unroll
  for (int t32 = 0; t32 < 2; ++t32) {
    const int rowK = t32 * 32 + qg;
    const int swk = (rowK ^ (rowK >> 3)) & 7;
#pragma unroll
    for (int dc = 0; dc < 4; ++dc)
      koff[t32][dc] = rowK * 128 + (((dc * 2 + half) ^ swk) << 4);
#pragma unroll
    for (int cc = 0; cc < 2; ++cc) {
      const int qw = ((t32 * 2 + cc) << 1) + half;
#pragma unroll
      for (int dt = 0; dt < 2; ++dt) {
        const int rowV = dt * 32 + qg;
        voff[t32][cc][dt] = rowV * 128 + ((qw ^ ((rowV ^ (rowV >> 3)) & 7)) << 4);
      }
    }
  }

  f32x16 oacc[2] = {};
  float lrun = 0.f;

  auto stage = [&](int bufi) {
    char* KsX = (char*)Ks[bufi];
    char* VsX = (char*)Vs[bufi];
    async_copy16(KsX + ldsc0, pK0);
    async_copy16(KsX + ldsc1, pK1);
    async_copy16(VsX + ldsc0, pV0);
    async_copy16(VsX + ldsc1, pV1);
    pK0 += (size_t)KVB * D_MODEL;
    pK1 += (size_t)KVB * D_MODEL;
    pV0 += KVB;
    pV1 += KVB;
  };

  auto process = [&](const char* KsC, const char* VsC) {
    // S'^T[kv][q] = K·(log2e·q-hat): lane holds q=l&31, kv=(reg&3)+8*(reg>>2)+4*half (+32*t32)
    f32x16 st[2] = {};
    __builtin_amdgcn_s_setprio(1);
#pragma unroll
    for (int t32 = 0; t32 < 2; ++t32)
#pragma unroll
      for (int dc = 0; dc < 4; ++dc) {
        bf16x8 kf = *(const bf16x8*)(KsC + koff[t32][dc]);
        st[t32] = MFMA32(kf, qf[dc], st[t32]);
      }
    __builtin_amdgcn_s_setprio(0);

    // p = exp2(s')  (global e^1 factor cancels between numerator and denominator)
    float rs0 = 0.f, rs1 = 0.f, rs2 = 0.f, rs3 = 0.f;
#pragma unroll
    for (int t32 = 0; t32 < 2; ++t32)
#pragma unroll
      for (int rr = 0; rr < 16; rr += 4) {
        float p0 = __builtin_amdgcn_exp2f(st[t32][rr + 0]);
        float p1 = __builtin_amdgcn_exp2f(st[t32][rr + 1]);
        float p2 = __builtin_amdgcn_exp2f(st[t32][rr + 2]);
        float p3 = __builtin_amdgcn_exp2f(st[t32][rr + 3]);
        st[t32][rr + 0] = p0; st[t32][rr + 1] = p1;
        st[t32][rr + 2] = p2; st[t32][rr + 3] = p3;
        rs0 += p0; rs1 += p1; rs2 += p2; rs3 += p3;
      }
    lrun += (rs0 + rs1) + (rs2 + rs3);

    // PV: O^T[dh][q] += V^T[dh][kv] * P[q][kv]
#pragma unroll
    for (int t32 = 0; t32 < 2; ++t32) {
#pragma unroll
      for (int cc = 0; cc < 2; ++cc) {
        const int base = cc * 8;
        u32 wA = cvtpk_bf16(st[t32][base + 0], st[t32][base + 1]);
        u32 wB = cvtpk_bf16(st[t32][base + 2], st[t32][base + 3]);
        u32 wC = cvtpk_bf16(st[t32][base + 4], st[t32][base + 5]);
        u32 wD = cvtpk_bf16(st[t32][base + 6], st[t32][base + 7]);
        permswap(wA, wC);
        permswap(wB, wD);
        u32x4 pw = {wA, wB, wC, wD};
        bf16x8 pf = __builtin_bit_cast(bf16x8, pw);
        __builtin_amdgcn_s_setprio(1);
#pragma unroll
        for (int dt = 0; dt < 2; ++dt) {
          bf16x8 vf = *(const bf16x8*)(VsC + voff[t32][cc][dt]);
          oacc[dt] = MFMA32(vf, pf, oacc[dt]);
        }
        __builtin_amdgcn_s_setprio(0);
      }
    }
  };

  // prologue: stage tiles 0 and 1, one full drain (also covers Q-frag loads)
  stage(0);
  stage(1);
  VMCNT(0);
  wg_barrier();

  // pair-unrolled main loop: tiles 0..NT-3 (buffer base compile-time per copy)
  for (int tp = 0; tp < NT / 2 - 1; ++tp) {
    VMCNT(4);               // tile 2tp landed; tile 2tp+1 stays in flight
    wg_barrier();
    process((const char*)Ks[0], (const char*)Vs[0]);
    wg_barrier();
    stage(0);               // tile 2tp+2
    VMCNT(4);
    wg_barrier();
    process((const char*)Ks[1], (const char*)Vs[1]);
    wg_barrier();
    stage(1);               // tile 2tp+3
  }
  // tile NT-2 (buf0): already staged, nothing more to stage
  VMCNT(4);
  wg_barrier();
  process((const char*)Ks[0], (const char*)Vs[0]);
  wg_barrier();
  // tile NT-1 (buf1): full drain
  VMCNT(0);
  wg_barrier();
  process((const char*)Ks[1], (const char*)Vs[1]);

  // epilogue: denom = own-half sum + other-half sum; pack pairs, u32 stores
  lrun += __shfl_xor(lrun, 32);
  const float inv = 1.0f / lrun;
  u32* orow = (u32*)(O + ((size_t)(b * SEQ + qt * 128 + wid * 32 + qg)) * D_MODEL + h * 64);
#pragma unroll
  for (int dt = 0; dt < 2; ++dt)
#pragma unroll
    for (int w = 0; w < 8; ++w) {
      const int dh = dt * 32 + (w & 1) * 2 + 8 * (w >> 1) + 4 * half;
      u32 pk = cvtpk_bf16(oacc[dt][2 * w] * inv, oacc[dt][2 * w + 1] * inv);
      orow[dh >> 1] = pk;
    }
}

// ---------------- launch ----------------
extern "C" void kernel_launch(void* const* d_in, const int* in_sizes, int n_in,
                              void* d_out, int out_size, void* d_ws, size_t ws_size,
                              hipStream_t stream) {
  const float* x   = (const float*)d_in[0];
  const float* ctx = (const float*)d_in[1];
  const float* Wq  = (const float*)d_in[2];
  const float* bq  = (const float*)d_in[3];
  const float* Wk  = (const float*)d_in[4];
  const float* bk  = (const float*)d_in[5];
  const float* Wv  = (const float*)d_in[6];
  const float* bv  = (const float*)d_in[7];
  const float* Wo  = (const float*)d_in[8];
  const float* bo  = (const float*)d_in[9];
  float* out = (float*)d_out;

  const size_t NTOK = (size_t)MTOT * D_MODEL; // 8M elems
  const size_t WSZ = (size_t)D_MODEL * D_MODEL;
  u16* xb  = (u16*)d_ws;       // x bf16; later reused as attention output
  u16* cb  = xb + NTOK;
  u16* wqb = cb + NTOK;
  u16* wkb = wqb + WSZ;        // wk,wv adjacent -> fused [K|V] GEMM B-panel
  u16* wvb = wkb + WSZ;
  u16* wob = wvb + WSZ;
  u16* Qb  = wob + WSZ;
  u16* Kb  = Qb + NTOK;
  u16* Vtb = Kb + NTOK;        // [b*16+h][dh][tok]
  (void)in_sizes; (void)n_in; (void)out_size; (void)ws_size;

  cvt_all<<<2048, 256, 0, stream>>>(x, ctx, Wq, Wk, Wv, Wo, xb, cb, wqb, wkb, wvb, wob);

  gemm_qkv<<<1536, 256, 0, stream>>>(xb, cb, wqb, wkb, bq, bk, bv, Qb, Kb, Vtb);

  attn_kernel<<<1024, 256, 0, stream>>>(Qb, Kb, Vtb, xb);

  gemm_out<<<512, 256, 0, stream>>>(xb, wob, bo, out);
}